// Round 9
// baseline (5119.816 us; speedup 1.0000x reference)
//
#include <hip/hip_runtime.h>
#include <hip/hip_bf16.h>
#include <stdint.h>

typedef short short8 __attribute__((ext_vector_type(8)));
typedef float f32x4 __attribute__((ext_vector_type(4)));
typedef unsigned uint4v __attribute__((ext_vector_type(4)));
typedef unsigned short u16;

__device__ __forceinline__ float bf2f(u16 b){ unsigned u = ((unsigned)b) << 16; float f; __builtin_memcpy(&f, &u, 4); return f; }
__device__ __forceinline__ u16 f2bf(float f){ unsigned u; __builtin_memcpy(&u, &f, 4); u = (u + 0x7fffu + ((u >> 16) & 1u)) >> 16; return (u16)u; }
__device__ __forceinline__ float sigm(float x){ return 1.f / (1.f + __expf(-x)); }
__device__ __forceinline__ float tanh_(float x){ float e = __expf(2.f * x); return 1.f - 2.f / (e + 1.f); }

// device-scope (coherence-point) accesses for the tagged h exchange
__device__ __forceinline__ uint4v ld_dev_u32x4(const unsigned* p){
  uint4v d; asm volatile("global_load_dwordx4 %0, %1, off sc0 sc1" : "=v"(d) : "v"(p) : "memory"); return d;
}
__device__ __forceinline__ void st_dev_u32(unsigned* p, unsigned v){
  asm volatile("global_store_dword %0, %1, off sc0 sc1" :: "v"(p), "v"(v) : "memory");
}
__device__ __forceinline__ void wait_vm0(){ asm volatile("s_waitcnt vmcnt(0)" ::: "memory"); }
__device__ __forceinline__ void sbar0(){ __builtin_amdgcn_sched_barrier(0); }

// ---------------- init: bf16 weights + full slab re-init (tags -> 0, buf1 seeded with s0) ------------
// slab (u32 words = (tag<<16)|bf16): [g(8)][buf(2)][slice(64)][row(8)][col(16)]
__global__ __launch_bounds__(256) void k_init(const float* __restrict__ Wih, const float* __restrict__ Whh,
                                              const float* __restrict__ s0,
                                              u16* __restrict__ Wihb, u16* __restrict__ Whhb,
                                              unsigned* __restrict__ slab)
{
  int i = blockIdx.x * 256 + threadIdx.x;          // grid 4096*256 = 1,048,576
  int n = 3072 * 1024;
  for (int idx = i; idx < n; idx += gridDim.x * 256){
    Wihb[idx] = f2bf(Wih[idx]);
    Whhb[idx] = f2bf(Whh[idx]);
  }
  if (i < 131072){                                  // whole slab rewritten every launch
    int col = i & 15, slice = (i >> 7) & 63, buf = (i >> 13) & 1;
    slab[i] = buf ? (unsigned)f2bf(s0[slice * 16 + col]) : 0u;   // tag 0
  }
}

// ---------------- xe = tanh(inputs @ W_e^T + b_e), stored bf16 [32768][1024] ----------------
__global__ __launch_bounds__(256) void k_xe(const float* __restrict__ inp, const float* __restrict__ We,
                                            const float* __restrict__ be, u16* __restrict__ xe)
{
  __shared__ float si[64][32];
  size_t m0 = (size_t)blockIdx.x * 64;
  int tid = threadIdx.x;
  for (int i = tid; i < 2048; i += 256)
    si[i >> 5][i & 31] = inp[m0 * 32 + i];
  __syncthreads();
  #pragma unroll
  for (int jj = 0; jj < 4; ++jj){
    int j = jj * 256 + tid;
    f32x4 wr[8];
    #pragma unroll
    for (int q = 0; q < 8; ++q)
      wr[q] = *(const f32x4*)(We + (size_t)j * 32 + q * 4);
    float bias = be[j];
    for (int mi = 0; mi < 64; ++mi){
      float acc = bias;
      #pragma unroll
      for (int q = 0; q < 8; ++q){
        f32x4 x = *(const f32x4*)(&si[mi][q * 4]);
        acc += x[0]*wr[q][0] + x[1]*wr[q][1] + x[2]*wr[q][2] + x[3]*wr[q][3];
      }
      xe[(m0 + mi) * 1024 + j] = f2bf(tanh_(acc));
    }
  }
}

// ---------------- xp = xe @ W_ih^T + b_ih, bf16 [32768][3072]; 128x128x32 MFMA tiles ----------------
__global__ __launch_bounds__(256) void k_xp(const u16* __restrict__ A, const u16* __restrict__ Bw,
                                            const float* __restrict__ bias, u16* __restrict__ C)
{
  __shared__ u16 As[128 * 32];
  __shared__ u16 Bs[128 * 32];
  int tid = threadIdx.x;
  int lane = tid & 63, wv = tid >> 6;
  int wr = wv >> 1, wc = wv & 1;
  int l15 = lane & 15, l4 = lane >> 4;
  int bid = blockIdx.x;
  int mb = bid / 24, nb = bid % 24;
  int m0 = mb * 128, n0 = nb * 128;

  int srow = tid >> 2;
  int sslot = tid & 3;
  int wb0 = srow * 64 + ((sslot ^ ((srow >> 1) & 3)) * 16);
  int swz = (l15 >> 1) & 3;
  int rb_ = l15 * 64 + ((l4 ^ swz) * 16);

  f32x4 acc[4][4] = {};
  const u16* Aptr = A + (size_t)m0 * 1024;
  const u16* Bptr = Bw + (size_t)n0 * 1024;

  for (int k0 = 0; k0 < 1024; k0 += 32){
    short8 va0 = *(const short8*)(Aptr + (size_t)srow * 1024 + k0 + sslot * 8);
    short8 va1 = *(const short8*)(Aptr + (size_t)(srow + 64) * 1024 + k0 + sslot * 8);
    short8 vb0 = *(const short8*)(Bptr + (size_t)srow * 1024 + k0 + sslot * 8);
    short8 vb1 = *(const short8*)(Bptr + (size_t)(srow + 64) * 1024 + k0 + sslot * 8);
    __syncthreads();
    *(short8*)((char*)As + wb0)        = va0;
    *(short8*)((char*)As + wb0 + 4096) = va1;
    *(short8*)((char*)Bs + wb0)        = vb0;
    *(short8*)((char*)Bs + wb0 + 4096) = vb1;
    __syncthreads();
    short8 af[4], bf[4];
    #pragma unroll
    for (int i = 0; i < 4; ++i){
      af[i] = *(const short8*)((const char*)As + (wr * 64 + i * 16) * 64 + rb_);
      bf[i] = *(const short8*)((const char*)Bs + (wc * 64 + i * 16) * 64 + rb_);
    }
    #pragma unroll
    for (int i = 0; i < 4; ++i)
      #pragma unroll
      for (int j = 0; j < 4; ++j)
        acc[i][j] = __builtin_amdgcn_mfma_f32_16x16x32_bf16(af[i], bf[j], acc[i][j], 0, 0, 0);
  }
  #pragma unroll
  for (int j = 0; j < 4; ++j){
    int n = n0 + wc * 64 + j * 16 + l15;
    float bv = bias[n];
    #pragma unroll
    for (int i = 0; i < 4; ++i){
      int mrow = m0 + wr * 64 + i * 16 + l4 * 4;
      #pragma unroll
      for (int r = 0; r < 4; ++r)
        C[(size_t)(mrow + r) * 3072 + n] = f2bf(acc[i][j][r] + bv);
    }
  }
}

// ---------------- GRU recurrence: two-chain pipeline, SELF-VALIDATING TAGGED h exchange --------------
// h word = (tag<<16)|bf16, tag = t+1 (dword stores are single-copy atomic: data+tag arrive together).
// Consumer polls the h words themselves until all tags match -- no flags, no producer store-ack.
// WAR safety: a producer reaches its t+1 overwrite of a buffer only after observing all h(t),
// which requires every WG's step-t reads of that buffer to have been served. k_init re-tags the
// whole slab each launch (replay-safe). Garbage MFMA A-rows 8-15 are zero (D rows 8-15 unused).
__global__ __launch_bounds__(256, 1) void k_rec(const u16* __restrict__ Whhb, const float* __restrict__ bhh,
                                                const u16* __restrict__ xpb, const float* __restrict__ s0,
                                                unsigned* __restrict__ slab, float* __restrict__ states)
{
  __shared__ f32x4 partA[4][3][64];
  __shared__ f32x4 partB[4][3][64];

  int w = blockIdx.x;
  int s = w & 63;                      // slice (cols s*16..s*16+16)
  int p = w >> 6;                      // pair 0..3
  int gA = 2 * p, gB = 2 * p + 1;
  int tid = threadIdx.x, lane = tid & 63, wv = tid >> 6;
  int l15 = lane & 15, l4 = lane >> 4;

  // persistent W_hh fragments (shared by both chains): lane l15 = col-in-slice, wave wv owns
  // k-range [wv*256, wv*256+256)
  short8 wreg[3][8];
  #pragma unroll
  for (int gt = 0; gt < 3; ++gt){
    const u16* wp = Whhb + (size_t)(gt * 1024 + s * 16 + l15) * 1024 + wv * 256 + l4 * 8;
    #pragma unroll
    for (int ks = 0; ks < 8; ++ks)
      wreg[gt][ks] = *(const short8*)(wp + ks * 32);
  }
  float bb[3];
  #pragma unroll
  for (int gt = 0; gt < 3; ++gt) bb[gt] = bhh[gt * 1024 + s * 16 + l15];
  float hA[4], hB[4];
  { float v = s0[s * 16 + l15];
    #pragma unroll
    for (int r = 0; r < 4; ++r){ hA[r] = v; hB[r] = v; } }

  const bool ownq = ((l15 >> 2) == wv) && (l4 < 2);
  const bool ldr  = (l15 < 8);                        // loader lanes (rows 0-7; rows 8-15 unused)
  int rowq = l4 * 4;
  int xrow = (l4 & 1) * 4;

  short8 af[8] = {};                                  // rows 8-15 stay zero
  uint4v vb[16];

  for (int t = 0; t < 512; ++t){
    int wb = t & 1, rb = wb ^ 1;
    unsigned expt = (unsigned)t;                      // expected tag: h(t-1) tagged t (seed tag 0)
    unsigned tgw  = (unsigned)(t + 1) << 16;          // produced tag

    // ---- xqA prefetch ----
    u16 xqA[12], xqB[12];
    #pragma unroll
    for (int gt = 0; gt < 3; ++gt)
      #pragma unroll
      for (int r = 0; r < 4; ++r)
        xqA[gt * 4 + r] = xpb[((size_t)(gA * 8 + xrow + r) * 512 + t) * 3072 + (size_t)gt * 1024 + s * 16 + l15];

    // ================= phase A: tagged poll-load =================
    {
      const unsigned* base = slab + ((size_t)(gA * 2 + rb) * 64) * 128;
      int guard = 0;
      while (true){
        if (ldr){
          #pragma unroll
          for (int ks = 0; ks < 8; ++ks){
            const unsigned* ap = base + ((size_t)(wv * 16 + ks * 2 + (l4 >> 1)) * 8 + l15) * 16 + (l4 & 1) * 8;
            vb[ks * 2]     = ld_dev_u32x4(ap);
            vb[ks * 2 + 1] = ld_dev_u32x4(ap + 4);
          }
        }
        wait_vm0(); sbar0();
        bool ok = true;
        if (ldr){
          #pragma unroll
          for (int i = 0; i < 16; ++i)
            #pragma unroll
            for (int j = 0; j < 4; ++j)
              ok = ok && ((vb[i][j] >> 16) == expt);
        }
        if (__all(ok)) break;
        __builtin_amdgcn_s_sleep(1);
        if (++guard > (1 << 15)) break;
      }
      sbar0();
      if (ldr){
        #pragma unroll
        for (int ks = 0; ks < 8; ++ks){
          uint4v a = vb[ks * 2], b = vb[ks * 2 + 1];
          uint4v pk;
          pk[0] = (a[0] & 0xffffu) | (a[1] << 16);
          pk[1] = (a[2] & 0xffffu) | (a[3] << 16);
          pk[2] = (b[0] & 0xffffu) | (b[1] << 16);
          pk[3] = (b[2] & 0xffffu) | (b[3] << 16);
          __builtin_memcpy(&af[ks], &pk, 16);
        }
      }
    }
    f32x4 acc[3] = {};
    #pragma unroll
    for (int ks = 0; ks < 8; ++ks)
      #pragma unroll
      for (int gt = 0; gt < 3; ++gt)
        acc[gt] = __builtin_amdgcn_mfma_f32_16x16x32_bf16(af[ks], wreg[gt][ks], acc[gt], 0, 0, 0);
    #pragma unroll
    for (int gt = 0; gt < 3; ++gt) partA[wv][gt][lane] = acc[gt];
    __syncthreads();
    float hnA[4];
    {
      f32x4 sr = partA[0][0][lane] + partA[1][0][lane] + partA[2][0][lane] + partA[3][0][lane];
      f32x4 sz = partA[0][1][lane] + partA[1][1][lane] + partA[2][1][lane] + partA[3][1][lane];
      f32x4 sn = partA[0][2][lane] + partA[1][2][lane] + partA[2][2][lane] + partA[3][2][lane];
      unsigned* hw = slab + (((size_t)(gA * 2 + wb) * 64 + s) * 8) * 16 + l15;
      #pragma unroll
      for (int r = 0; r < 4; ++r){
        float rr = sigm(bf2f(xqA[r])     + sr[r] + bb[0]);
        float zz = sigm(bf2f(xqA[4 + r]) + sz[r] + bb[1]);
        float nn = tanh_(bf2f(xqA[8 + r]) + rr * (sn[r] + bb[2]));
        hnA[r] = (1.f - zz) * nn + zz * hA[r];
        hA[r] = hnA[r];
        if (ownq) st_dev_u32(hw + (size_t)(rowq + r) * 16, tgw | f2bf(hnA[r]));  // fire-and-forget
      }
    }
    if (ownq){
      #pragma unroll
      for (int r = 0; r < 4; ++r)
        states[((size_t)(gA * 8 + rowq + r) * 512 + t) * 1024 + s * 16 + l15] = hnA[r];
    }
    #pragma unroll
    for (int gt = 0; gt < 3; ++gt)
      #pragma unroll
      for (int r = 0; r < 4; ++r)
        xqB[gt * 4 + r] = xpb[((size_t)(gB * 8 + xrow + r) * 512 + t) * 3072 + (size_t)gt * 1024 + s * 16 + l15];

    // ================= phase B: tagged poll-load =================
    {
      const unsigned* base = slab + ((size_t)(gB * 2 + rb) * 64) * 128;
      int guard = 0;
      while (true){
        if (ldr){
          #pragma unroll
          for (int ks = 0; ks < 8; ++ks){
            const unsigned* ap = base + ((size_t)(wv * 16 + ks * 2 + (l4 >> 1)) * 8 + l15) * 16 + (l4 & 1) * 8;
            vb[ks * 2]     = ld_dev_u32x4(ap);
            vb[ks * 2 + 1] = ld_dev_u32x4(ap + 4);
          }
        }
        wait_vm0(); sbar0();
        bool ok = true;
        if (ldr){
          #pragma unroll
          for (int i = 0; i < 16; ++i)
            #pragma unroll
            for (int j = 0; j < 4; ++j)
              ok = ok && ((vb[i][j] >> 16) == expt);
        }
        if (__all(ok)) break;
        __builtin_amdgcn_s_sleep(1);
        if (++guard > (1 << 15)) break;
      }
      sbar0();
      if (ldr){
        #pragma unroll
        for (int ks = 0; ks < 8; ++ks){
          uint4v a = vb[ks * 2], b = vb[ks * 2 + 1];
          uint4v pk;
          pk[0] = (a[0] & 0xffffu) | (a[1] << 16);
          pk[1] = (a[2] & 0xffffu) | (a[3] << 16);
          pk[2] = (b[0] & 0xffffu) | (b[1] << 16);
          pk[3] = (b[2] & 0xffffu) | (b[3] << 16);
          __builtin_memcpy(&af[ks], &pk, 16);
        }
      }
    }
    f32x4 accB[3] = {};
    #pragma unroll
    for (int ks = 0; ks < 8; ++ks)
      #pragma unroll
      for (int gt = 0; gt < 3; ++gt)
        accB[gt] = __builtin_amdgcn_mfma_f32_16x16x32_bf16(af[ks], wreg[gt][ks], accB[gt], 0, 0, 0);
    #pragma unroll
    for (int gt = 0; gt < 3; ++gt) partB[wv][gt][lane] = accB[gt];
    __syncthreads();
    float hnB[4];
    {
      f32x4 sr = partB[0][0][lane] + partB[1][0][lane] + partB[2][0][lane] + partB[3][0][lane];
      f32x4 sz = partB[0][1][lane] + partB[1][1][lane] + partB[2][1][lane] + partB[3][1][lane];
      f32x4 sn = partB[0][2][lane] + partB[1][2][lane] + partB[2][2][lane] + partB[3][2][lane];
      unsigned* hw = slab + (((size_t)(gB * 2 + wb) * 64 + s) * 8) * 16 + l15;
      #pragma unroll
      for (int r = 0; r < 4; ++r){
        float rr = sigm(bf2f(xqB[r])     + sr[r] + bb[0]);
        float zz = sigm(bf2f(xqB[4 + r]) + sz[r] + bb[1]);
        float nn = tanh_(bf2f(xqB[8 + r]) + rr * (sn[r] + bb[2]));
        hnB[r] = (1.f - zz) * nn + zz * hB[r];
        hB[r] = hnB[r];
        if (ownq) st_dev_u32(hw + (size_t)(rowq + r) * 16, tgw | f2bf(hnB[r]));
      }
    }
    if (ownq){
      #pragma unroll
      for (int r = 0; r < 4; ++r)
        states[((size_t)(gB * 8 + rowq + r) * 512 + t) * 1024 + s * 16 + l15] = hnB[r];
    }
  }
}

// ---------------- outputs = states @ W_ly^T, pure fp32 ----------------
__global__ __launch_bounds__(256) void k_out(const float* __restrict__ st, const float* __restrict__ Wly,
                                             float* __restrict__ out)
{
  __shared__ float srow[8][1024];
  size_t m0 = (size_t)blockIdx.x * 8;
  int tid = threadIdx.x;
  for (int i = tid; i < 8 * 1024; i += 256)
    srow[i >> 10][i & 1023] = st[(m0 + (i >> 10)) * 1024 + (i & 1023)];
  __syncthreads();
  int mi = tid >> 5, o = tid & 31;
  const float* wp = Wly + (size_t)o * 1024;
  float acc = 0.f;
  #pragma unroll 4
  for (int k = 0; k < 1024; k += 4){
    f32x4 w = *(const f32x4*)(wp + k);
    f32x4 x = *(const f32x4*)(&srow[mi][k]);
    acc += x[0]*w[0] + x[1]*w[1] + x[2]*w[2] + x[3]*w[3];
  }
  out[(m0 + mi) * 32 + o] = acc;
}

extern "C" void kernel_launch(void* const* d_in, const int* in_sizes, int n_in,
                              void* d_out, int out_size, void* d_ws, size_t ws_size,
                              hipStream_t stream)
{
  const float* inputs = (const float*)d_in[0];
  const float* s0     = (const float*)d_in[1];
  const float* We     = (const float*)d_in[2];
  const float* be     = (const float*)d_in[3];
  const float* Wih    = (const float*)d_in[4];
  const float* bih    = (const float*)d_in[5];
  const float* Whh    = (const float*)d_in[6];
  const float* bhh    = (const float*)d_in[7];
  const float* Wly    = (const float*)d_in[8];

  float* out    = (float*)d_out;                 // (B,T,32)
  float* states = out + (size_t)64 * 512 * 32;   // (B,T,1024)

  char* ws = (char*)d_ws;
  u16* xe        = (u16*)ws;       ws += (size_t)32768 * 1024 * 2;
  u16* xpb       = (u16*)ws;       ws += (size_t)32768 * 3072 * 2;
  u16* Wihb      = (u16*)ws;       ws += (size_t)3072 * 1024 * 2;
  u16* Whhb      = (u16*)ws;       ws += (size_t)3072 * 1024 * 2;
  unsigned* slab = (unsigned*)ws;  ws += (size_t)8 * 2 * 64 * 8 * 16 * 4;   // tagged h, 512 KB

  k_init<<<dim3(4096), dim3(256), 0, stream>>>(Wih, Whh, s0, Wihb, Whhb, slab);
  k_xe<<<dim3(512), dim3(256), 0, stream>>>(inputs, We, be, xe);
  k_xp<<<dim3(6144), dim3(256), 0, stream>>>(xe, Wihb, bih, xpb);

  void* args[] = { (void*)&Whhb, (void*)&bhh, (void*)&xpb, (void*)&s0,
                   (void*)&slab, (void*)&states };
  hipError_t e = hipLaunchCooperativeKernel((const void*)k_rec, dim3(256), dim3(256), args, 0, stream);
  if (e != hipSuccess){
    (void)hipGetLastError();
    k_rec<<<dim3(256), dim3(256), 0, stream>>>(Whhb, bhh, xpb, s0, slab, states);
  }
  k_out<<<dim3(4096), dim3(256), 0, stream>>>(states, Wly, out);
}

// Round 10
// 5102.390 us; speedup vs baseline: 1.0034x; 1.0034x over previous
//
#include <hip/hip_runtime.h>
#include <hip/hip_bf16.h>
#include <stdint.h>

typedef short short8 __attribute__((ext_vector_type(8)));
typedef float f32x4 __attribute__((ext_vector_type(4)));
typedef unsigned short u16;

__device__ __forceinline__ float bf2f(u16 b){ unsigned u = ((unsigned)b) << 16; float f; __builtin_memcpy(&f, &u, 4); return f; }
__device__ __forceinline__ u16 f2bf(float f){ unsigned u; __builtin_memcpy(&u, &f, 4); u = (u + 0x7fffu + ((u >> 16) & 1u)) >> 16; return (u16)u; }
__device__ __forceinline__ float sigm(float x){ return 1.f / (1.f + __expf(-x)); }
__device__ __forceinline__ float tanh_(float x){ float e = __expf(2.f * x); return 1.f - 2.f / (e + 1.f); }

// device-scope (coherence-point) accesses for h/flag exchange (r3-proven protocol)
__device__ __forceinline__ short8 ld_devx4(const u16* p){
  short8 d; asm volatile("global_load_dwordx4 %0, %1, off sc0 sc1" : "=v"(d) : "v"(p) : "memory"); return d;
}
__device__ __forceinline__ int ld_dev_u32(const int* p){
  int d; asm volatile("global_load_dword %0, %1, off sc0 sc1" : "=v"(d) : "v"(p) : "memory"); return d;
}
__device__ __forceinline__ void st_dev_u16(u16* p, u16 v){
  asm volatile("global_store_short %0, %1, off sc0 sc1" :: "v"(p), "v"(v) : "memory");
}
__device__ __forceinline__ void st_dev_u32(int* p, int v){
  asm volatile("global_store_dword %0, %1, off sc0 sc1" :: "v"(p), "v"(v) : "memory");
}
__device__ __forceinline__ void wait_vm0(){ asm volatile("s_waitcnt vmcnt(0)" ::: "memory"); }
__device__ __forceinline__ void sbar0(){ __builtin_amdgcn_sched_barrier(0); }

// ---------------- init: bf16 weights, zero flags, h(-1)=state0 into slab buf 1 ----------------
// slab: [g(4)][buf(2)][slice(128)][batch(16)][col(8)] bf16 ; flags: [g(4)][t(512)][slice(128)]
__global__ __launch_bounds__(256) void k_init(const float* __restrict__ Wih, const float* __restrict__ Whh,
                                              const float* __restrict__ s0,
                                              u16* __restrict__ Wihb, u16* __restrict__ Whhb,
                                              u16* __restrict__ slab, int* __restrict__ flags)
{
  int i = blockIdx.x * 256 + threadIdx.x;          // grid 4096*256 = 1,048,576
  int n = 3072 * 1024;
  for (int idx = i; idx < n; idx += gridDim.x * 256){
    Wihb[idx] = f2bf(Wih[idx]);
    Whhb[idx] = f2bf(Whh[idx]);
  }
  if (i < 4 * 512 * 128) flags[i] = 0;             // re-zero every launch (replay-safe)
  if (i < 4 * 128 * 128){                          // seed buf1 with s0: i = g*16384 + slice*128 + row*8 + col
    int g = i >> 14, rem = i & 16383;
    int slice = rem >> 7, col = i & 7;
    slab[((size_t)(g * 2 + 1)) * 16384 + rem] = f2bf(s0[slice * 8 + col]);
  }
}

// ---------------- xe = tanh(inputs @ W_e^T + b_e), stored bf16 [32768][1024] ----------------
__global__ __launch_bounds__(256) void k_xe(const float* __restrict__ inp, const float* __restrict__ We,
                                            const float* __restrict__ be, u16* __restrict__ xe)
{
  __shared__ float si[64][32];
  size_t m0 = (size_t)blockIdx.x * 64;
  int tid = threadIdx.x;
  for (int i = tid; i < 2048; i += 256)
    si[i >> 5][i & 31] = inp[m0 * 32 + i];
  __syncthreads();
  #pragma unroll
  for (int jj = 0; jj < 4; ++jj){
    int j = jj * 256 + tid;
    f32x4 wr[8];
    #pragma unroll
    for (int q = 0; q < 8; ++q)
      wr[q] = *(const f32x4*)(We + (size_t)j * 32 + q * 4);
    float bias = be[j];
    for (int mi = 0; mi < 64; ++mi){
      float acc = bias;
      #pragma unroll
      for (int q = 0; q < 8; ++q){
        f32x4 x = *(const f32x4*)(&si[mi][q * 4]);
        acc += x[0]*wr[q][0] + x[1]*wr[q][1] + x[2]*wr[q][2] + x[3]*wr[q][3];
      }
      xe[(m0 + mi) * 1024 + j] = f2bf(tanh_(acc));
    }
  }
}

// ---------------- xp = xe @ W_ih^T + b_ih; 128x128x32 tiles, global_load_lds staging ----------------
__global__ __launch_bounds__(256) void k_xp(const u16* __restrict__ A, const u16* __restrict__ Bw,
                                            const float* __restrict__ bias, u16* __restrict__ C)
{
  __shared__ u16 As[128 * 32];                 // linear [row][k], 8 KB
  __shared__ u16 Bs[128 * 32];
  int tid = threadIdx.x, lane = tid & 63, wv = tid >> 6;
  int wr = wv >> 1, wc = wv & 1;
  int l15 = lane & 15, l4 = lane >> 4;
  int bid = blockIdx.x;
  int mb = bid / 24, nb = bid % 24;
  int m0 = mb * 128, n0 = nb * 128;

  // staging: wave wv fills LDS rows [wv*32, wv*32+32); lane -> row wv*32 + chunkrow, k (lane&3)*8
  int srow = lane >> 2, skk = (lane & 3) * 8;
  const u16* Ab = A + ((size_t)m0 + wv * 32 + srow) * 1024 + skk;
  const u16* Bb = Bw + ((size_t)n0 + wv * 32 + srow) * 1024 + skk;

  f32x4 acc[4][4] = {};
  for (int k0 = 0; k0 < 1024; k0 += 32){
    __syncthreads();                           // prior reads complete before overwrite
    __builtin_amdgcn_global_load_lds(Ab + k0,              &As[(wv * 2)     * 512], 16, 0, 0);
    __builtin_amdgcn_global_load_lds(Ab + k0 + 16 * 1024,  &As[(wv * 2 + 1) * 512], 16, 0, 0);
    __builtin_amdgcn_global_load_lds(Bb + k0,              &Bs[(wv * 2)     * 512], 16, 0, 0);
    __builtin_amdgcn_global_load_lds(Bb + k0 + 16 * 1024,  &Bs[(wv * 2 + 1) * 512], 16, 0, 0);
    __syncthreads();                           // compiler drains vmcnt before s_barrier
    short8 af[4], bf[4];
    #pragma unroll
    for (int i = 0; i < 4; ++i){
      af[i] = *(const short8*)(As + (size_t)(wr * 64 + i * 16 + l15) * 32 + l4 * 8);
      bf[i] = *(const short8*)(Bs + (size_t)(wc * 64 + i * 16 + l15) * 32 + l4 * 8);
    }
    #pragma unroll
    for (int i = 0; i < 4; ++i)
      #pragma unroll
      for (int j = 0; j < 4; ++j)
        acc[i][j] = __builtin_amdgcn_mfma_f32_16x16x32_bf16(af[i], bf[j], acc[i][j], 0, 0, 0);
  }
  #pragma unroll
  for (int j = 0; j < 4; ++j){
    int n = n0 + wc * 64 + j * 16 + l15;
    float bv = bias[n];
    #pragma unroll
    for (int i = 0; i < 4; ++i){
      int mrow = m0 + wr * 64 + i * 16 + l4 * 4;
      #pragma unroll
      for (int r = 0; r < 4; ++r)
        C[(size_t)(mrow + r) * 3072 + n] = f2bf(acc[i][j][r] + bv);
    }
  }
}

// ---------------- GRU recurrence: barrier-free single-wave slice engines ----------------
// 4 groups x 16 batch; 128 slices/group of 8 h-cols x 3 gates; block = 1 wave = 1 slice engine.
// Weights (3x8x1024 bf16 = 48KB) staged once in LDS; h A-frags (full K) in 128 VGPRs.
// Per step: poll ALL 128 flags(t-1) -> 32 coalesced h loads -> 96 {ds_read+MFMA} -> gate
// (all 64 lanes) -> 8x16 h store -> vmcnt0 -> flag. No __syncthreads in the loop.
// WAR: a wave overwrites buf W(t)=R(t-1) only after observing all flags(t-1), i.e. after
// every block's step-(t-1) reads of that buffer were served (reads precede each flag).
__global__ __launch_bounds__(64, 1) void k_rec(const u16* __restrict__ Whhb, const float* __restrict__ bhh,
                                               const u16* __restrict__ xpb, const float* __restrict__ s0,
                                               u16* __restrict__ slab, int* __restrict__ flags,
                                               float* __restrict__ states)
{
  __shared__ u16 wlds[3 * 32 * 256];          // [gate][kstep(32)][col(8)][dk(32)] = 48 KB
  int b = blockIdx.x;
  int g = b >> 7;                             // group 0..3
  int s = b & 127;                            // slice 0..127 (cols s*8 .. s*8+8)
  int lane = threadIdx.x;
  int l15 = lane & 15, l4 = lane >> 4;
  int c7 = l15 & 7;

  // ---- stage W slice -> LDS (one-time, pipelined) ----
  {
    int jbit = lane >> 5;                     // 0..1
    int c    = (lane >> 2) & 7;
    int dk   = (lane & 3) * 8;
    #pragma unroll 1
    for (int gt = 0; gt < 3; ++gt){
      const u16* wp = Whhb + (size_t)(gt * 1024 + s * 8 + c) * 1024 + dk;
      #pragma unroll 4
      for (int jj = 0; jj < 16; ++jj){
        int j = jj * 2 + jbit;
        short8 v = *(const short8*)(wp + j * 32);
        *(short8*)(wlds + ((gt * 32 + j) * 256) + c * 32 + dk) = v;
      }
    }
  }
  float bb0 = bhh[s * 8 + c7], bb1 = bhh[1024 + s * 8 + c7], bb2 = bhh[2048 + s * 8 + c7];
  float h[4];
  { float v = s0[s * 8 + c7]; h[0] = h[1] = h[2] = h[3] = v; }

  for (int t = 0; t < 512; ++t){
    int wb = t & 1, rb = wb ^ 1;
    // xq: 3 gates x 4 batch rows for this lane's (row=l4*4+r, col=c7)
    u16 xq[12];
    #pragma unroll
    for (int gt = 0; gt < 3; ++gt)
      #pragma unroll
      for (int r = 0; r < 4; ++r)
        xq[gt * 4 + r] = xpb[((size_t)(g * 16 + l4 * 4 + r) * 512 + t) * 3072 + gt * 1024 + s * 8 + c7];

    if (t > 0){
      const int* fp = flags + ((size_t)g * 512 + (t - 1)) * 128 + lane;
      int guard = 0;
      while (true){
        int v0 = ld_dev_u32(fp);
        int v1 = ld_dev_u32(fp + 64);
        wait_vm0(); sbar0();
        if (__all((v0 != 0) && (v1 != 0))) break;
        __builtin_amdgcn_s_sleep(1);
        if (++guard > (1 << 14)) break;       // bail visibly, never hang
      }
      sbar0();
    }
    // A-frags: full h(t-1) x 16 batch; kstep j k-range = slices j*4..j*4+4; 1KB/instr coalesced
    const u16* hb = slab + (size_t)(g * 2 + rb) * 16384;
    short8 af[32];
    #pragma unroll
    for (int j = 0; j < 32; ++j)
      af[j] = ld_devx4(hb + (size_t)(j * 4 + l4) * 128 + l15 * 8);
    wait_vm0(); sbar0();
    f32x4 a0 = {}, a1 = {}, a2 = {};
    #pragma unroll
    for (int j = 0; j < 32; ++j){
      short8 b0 = *(const short8*)(wlds + (size_t)j * 256 + c7 * 32 + l4 * 8);
      short8 b1 = *(const short8*)(wlds + (size_t)(32 + j) * 256 + c7 * 32 + l4 * 8);
      short8 b2 = *(const short8*)(wlds + (size_t)(64 + j) * 256 + c7 * 32 + l4 * 8);
      a0 = __builtin_amdgcn_mfma_f32_16x16x32_bf16(af[j], b0, a0, 0, 0, 0);
      a1 = __builtin_amdgcn_mfma_f32_16x16x32_bf16(af[j], b1, a1, 0, 0, 0);
      a2 = __builtin_amdgcn_mfma_f32_16x16x32_bf16(af[j], b2, a2, 0, 0, 0);
    }
    // gate: D row = l4*4+r (batch), col = l15 (cols >=8 are duplicates, not stored)
    u16* hw = slab + (size_t)(g * 2 + wb) * 16384 + (size_t)s * 128;
    float hn[4];
    #pragma unroll
    for (int r = 0; r < 4; ++r){
      float rr = sigm(bf2f(xq[r])      + a0[r] + bb0);
      float zz = sigm(bf2f(xq[4 + r])  + a1[r] + bb1);
      float nn = tanh_(bf2f(xq[8 + r]) + rr * (a2[r] + bb2));
      hn[r] = (1.f - zz) * nn + zz * h[r];
      h[r] = hn[r];
      if (l15 < 8) st_dev_u16(hw + (l4 * 4 + r) * 8 + l15, f2bf(hn[r]));
    }
    wait_vm0(); sbar0();                      // h applied at coherence point
    if (lane == 0)
      st_dev_u32(flags + ((size_t)g * 512 + t) * 128 + s, 1);
    if (l15 < 8){
      #pragma unroll
      for (int r = 0; r < 4; ++r)
        states[((size_t)(g * 16 + l4 * 4 + r) * 512 + t) * 1024 + s * 8 + l15] = hn[r];
    }
  }
}

// ---------------- outputs = states @ W_ly^T, pure fp32 ----------------
__global__ __launch_bounds__(256) void k_out(const float* __restrict__ st, const float* __restrict__ Wly,
                                             float* __restrict__ out)
{
  __shared__ float srow[8][1024];
  size_t m0 = (size_t)blockIdx.x * 8;
  int tid = threadIdx.x;
  for (int i = tid; i < 8 * 1024; i += 256)
    srow[i >> 10][i & 1023] = st[(m0 + (i >> 10)) * 1024 + (i & 1023)];
  __syncthreads();
  int mi = tid >> 5, o = tid & 31;
  const float* wp = Wly + (size_t)o * 1024;
  float acc = 0.f;
  #pragma unroll 4
  for (int k = 0; k < 1024; k += 4){
    f32x4 w = *(const f32x4*)(wp + k);
    f32x4 x = *(const f32x4*)(&srow[mi][k]);
    acc += x[0]*w[0] + x[1]*w[1] + x[2]*w[2] + x[3]*w[3];
  }
  out[(m0 + mi) * 32 + o] = acc;
}

extern "C" void kernel_launch(void* const* d_in, const int* in_sizes, int n_in,
                              void* d_out, int out_size, void* d_ws, size_t ws_size,
                              hipStream_t stream)
{
  const float* inputs = (const float*)d_in[0];
  const float* s0     = (const float*)d_in[1];
  const float* We     = (const float*)d_in[2];
  const float* be     = (const float*)d_in[3];
  const float* Wih    = (const float*)d_in[4];
  const float* bih    = (const float*)d_in[5];
  const float* Whh    = (const float*)d_in[6];
  const float* bhh    = (const float*)d_in[7];
  const float* Wly    = (const float*)d_in[8];

  float* out    = (float*)d_out;                 // (B,T,32)
  float* states = out + (size_t)64 * 512 * 32;   // (B,T,1024)

  char* ws = (char*)d_ws;
  u16* xe    = (u16*)ws;  ws += (size_t)32768 * 1024 * 2;
  u16* xpb   = (u16*)ws;  ws += (size_t)32768 * 3072 * 2;
  u16* Wihb  = (u16*)ws;  ws += (size_t)3072 * 1024 * 2;
  u16* Whhb  = (u16*)ws;  ws += (size_t)3072 * 1024 * 2;
  u16* slab  = (u16*)ws;  ws += (size_t)4 * 2 * 128 * 16 * 8 * 2;  // [g][buf][slice][16][8] bf16
  int* flags = (int*)ws;  ws += (size_t)4 * 512 * 128 * 4;         // [g][t][slice]

  k_init<<<dim3(4096), dim3(256), 0, stream>>>(Wih, Whh, s0, Wihb, Whhb, slab, flags);
  k_xe<<<dim3(512), dim3(256), 0, stream>>>(inputs, We, be, xe);
  k_xp<<<dim3(6144), dim3(256), 0, stream>>>(xe, Wihb, bih, xpb);

  void* args[] = { (void*)&Whhb, (void*)&bhh, (void*)&xpb, (void*)&s0,
                   (void*)&slab, (void*)&flags, (void*)&states };
  hipError_t e = hipLaunchCooperativeKernel((const void*)k_rec, dim3(512), dim3(64), args, 0, stream);
  if (e != hipSuccess){
    (void)hipGetLastError();
    k_rec<<<dim3(512), dim3(64), 0, stream>>>(Whhb, bhh, xpb, s0, slab, flags, states);
  }
  k_out<<<dim3(4096), dim3(256), 0, stream>>>(states, Wly, out);
}

// Round 11
// 3594.047 us; speedup vs baseline: 1.4245x; 1.4197x over previous
//
#include <hip/hip_runtime.h>
#include <hip/hip_bf16.h>
#include <stdint.h>

typedef short short8 __attribute__((ext_vector_type(8)));
typedef float f32x4 __attribute__((ext_vector_type(4)));
typedef unsigned short u16;

__device__ __forceinline__ float bf2f(u16 b){ unsigned u = ((unsigned)b) << 16; float f; __builtin_memcpy(&f, &u, 4); return f; }
__device__ __forceinline__ u16 f2bf(float f){ unsigned u; __builtin_memcpy(&u, &f, 4); u = (u + 0x7fffu + ((u >> 16) & 1u)) >> 16; return (u16)u; }
__device__ __forceinline__ float sigm(float x){ return 1.f / (1.f + __expf(-x)); }
__device__ __forceinline__ float tanh_(float x){ float e = __expf(2.f * x); return 1.f - 2.f / (e + 1.f); }

// device-scope (coherence-point) accesses -- r3-proven protocol, verbatim
__device__ __forceinline__ short8 ld_cohx4(const u16* p){
  short8 d;
  asm volatile("global_load_dwordx4 %0, %1, off sc0 sc1" : "=v"(d) : "v"(p) : "memory");
  return d;
}
__device__ __forceinline__ int ld_coh_u32(const int* p){
  int d;
  asm volatile("global_load_dword %0, %1, off sc0 sc1" : "=v"(d) : "v"(p) : "memory");
  return d;
}
__device__ __forceinline__ void st_coh_u16(u16* p, u16 v){
  asm volatile("global_store_short %0, %1, off sc0 sc1" :: "v"(p), "v"(v) : "memory");
}
__device__ __forceinline__ void st_coh_u32(int* p, int v){
  asm volatile("global_store_dword %0, %1, off sc0 sc1" :: "v"(p), "v"(v) : "memory");
}
__device__ __forceinline__ void wait_vm0(){ asm volatile("s_waitcnt vmcnt(0)" ::: "memory"); }

// ---------------- init: bf16 weights, zero flags, h(-1)=state0 into slab buf 1 ----------------
// hslab layout: [buf(2)][g(4)][slice(64)][row(16)][col(16)] bf16  (512B per slice)
__global__ __launch_bounds__(256) void k_init(const float* __restrict__ Wih, const float* __restrict__ Whh,
                                              const float* __restrict__ s0,
                                              u16* __restrict__ Wihb, u16* __restrict__ Whhb,
                                              u16* __restrict__ hslab, int* __restrict__ flags)
{
  int i = blockIdx.x * 256 + threadIdx.x;
  int n = 3072 * 1024;
  for (int idx = i; idx < n; idx += gridDim.x * 256){
    Wihb[idx] = f2bf(Wih[idx]);
    Whhb[idx] = f2bf(Whh[idx]);
  }
  if (i < 65536){
    int k = ((i >> 8) & 63) * 16 + (i & 15);   // slice*16 + col
    hslab[65536 + i] = f2bf(s0[k]);
  }
  if (i < 4 * 512 * 64) flags[i] = 0;          // per-launch re-zero (graph replay safe)
}

// ---------------- xe = tanh(inputs @ W_e^T + b_e), stored bf16 [32768][1024] ----------------
__global__ __launch_bounds__(256) void k_xe(const float* __restrict__ inp, const float* __restrict__ We,
                                            const float* __restrict__ be, u16* __restrict__ xe)
{
  __shared__ float si[64][32];
  size_t m0 = (size_t)blockIdx.x * 64;
  int tid = threadIdx.x;
  for (int i = tid; i < 2048; i += 256)
    si[i >> 5][i & 31] = inp[m0 * 32 + i];
  __syncthreads();
  #pragma unroll
  for (int jj = 0; jj < 4; ++jj){
    int j = jj * 256 + tid;
    f32x4 wr[8];
    #pragma unroll
    for (int q = 0; q < 8; ++q)
      wr[q] = *(const f32x4*)(We + (size_t)j * 32 + q * 4);
    float bias = be[j];
    for (int mi = 0; mi < 64; ++mi){
      float acc = bias;
      #pragma unroll
      for (int q = 0; q < 8; ++q){
        f32x4 x = *(const f32x4*)(&si[mi][q * 4]);
        acc += x[0]*wr[q][0] + x[1]*wr[q][1] + x[2]*wr[q][2] + x[3]*wr[q][3];
      }
      xe[(m0 + mi) * 1024 + j] = f2bf(tanh_(acc));
    }
  }
}

// ---------------- xp = xe @ W_ih^T + b_ih; 128x128x32 tiles, global_load_lds staging (r10-validated) --
__global__ __launch_bounds__(256) void k_xp(const u16* __restrict__ A, const u16* __restrict__ Bw,
                                            const float* __restrict__ bias, u16* __restrict__ C)
{
  __shared__ u16 As[128 * 32];                 // linear [row][k], 8 KB
  __shared__ u16 Bs[128 * 32];
  int tid = threadIdx.x, lane = tid & 63, wv = tid >> 6;
  int wr = wv >> 1, wc = wv & 1;
  int l15 = lane & 15, l4 = lane >> 4;
  int bid = blockIdx.x;
  int mb = bid / 24, nb = bid % 24;
  int m0 = mb * 128, n0 = nb * 128;

  int srow = lane >> 2, skk = (lane & 3) * 8;
  const u16* Ab = A + ((size_t)m0 + wv * 32 + srow) * 1024 + skk;
  const u16* Bb = Bw + ((size_t)n0 + wv * 32 + srow) * 1024 + skk;

  f32x4 acc[4][4] = {};
  for (int k0 = 0; k0 < 1024; k0 += 32){
    __syncthreads();                           // prior reads complete before overwrite
    __builtin_amdgcn_global_load_lds(Ab + k0,              &As[(wv * 2)     * 512], 16, 0, 0);
    __builtin_amdgcn_global_load_lds(Ab + k0 + 16 * 1024,  &As[(wv * 2 + 1) * 512], 16, 0, 0);
    __builtin_amdgcn_global_load_lds(Bb + k0,              &Bs[(wv * 2)     * 512], 16, 0, 0);
    __builtin_amdgcn_global_load_lds(Bb + k0 + 16 * 1024,  &Bs[(wv * 2 + 1) * 512], 16, 0, 0);
    __syncthreads();                           // compiler drains vmcnt before s_barrier
    short8 af[4], bf[4];
    #pragma unroll
    for (int i = 0; i < 4; ++i){
      af[i] = *(const short8*)(As + (size_t)(wr * 64 + i * 16 + l15) * 32 + l4 * 8);
      bf[i] = *(const short8*)(Bs + (size_t)(wc * 64 + i * 16 + l15) * 32 + l4 * 8);
    }
    #pragma unroll
    for (int i = 0; i < 4; ++i)
      #pragma unroll
      for (int j = 0; j < 4; ++j)
        acc[i][j] = __builtin_amdgcn_mfma_f32_16x16x32_bf16(af[i], bf[j], acc[i][j], 0, 0, 0);
  }
  #pragma unroll
  for (int j = 0; j < 4; ++j){
    int n = n0 + wc * 64 + j * 16 + l15;
    float bv = bias[n];
    #pragma unroll
    for (int i = 0; i < 4; ++i){
      int mrow = m0 + wr * 64 + i * 16 + l4 * 4;
      #pragma unroll
      for (int r = 0; r < 4; ++r)
        C[(size_t)(mrow + r) * 3072 + n] = f2bf(acc[i][j][r] + bv);
    }
  }
}

// ---------------- GRU recurrence: r3-verbatim (4 groups x 16 batch; 64 WGs/group; 1 WG/CU) ----------
// WG (g,s): owns h cols [s*16,s*16+16) for 3 gates; W_hh fragments VGPR-resident.
// h exchange slice-major (512B/slice); each wave polls ONLY its own 16 source slices.
__global__ __launch_bounds__(256, 1) void k_rec(const u16* __restrict__ Whhb, const float* __restrict__ bhh,
                                                const u16* __restrict__ xpb, const float* __restrict__ s0,
                                                u16* __restrict__ hslab, float* __restrict__ states,
                                                int* __restrict__ flags)
{
  int w = blockIdx.x;
  int g = w & 3;                 // group
  int s = w >> 2;                // slice 0..63
  int jb = s * 16;
  int tid = threadIdx.x, lane = tid & 63, wv = tid >> 6;
  int l15 = lane & 15, l4 = lane >> 4;

  // persistent W_hh fragments: lane l15 = col-in-slice, wave wv owns K [wv*256, +256)
  short8 wreg[3][8];
  #pragma unroll
  for (int gt = 0; gt < 3; ++gt){
    const u16* wp = Whhb + (size_t)(gt * 1024 + jb + l15) * 1024 + wv * 256 + l4 * 8;
    #pragma unroll
    for (int ks = 0; ks < 8; ++ks)
      wreg[gt][ks] = *(const short8*)(wp + ks * 32);
  }
  float bb0 = bhh[jb + l15], bb1 = bhh[1024 + jb + l15], bb2 = bhh[2048 + jb + l15];
  float hreg[4];
  { float v = s0[jb + l15]; hreg[0] = hreg[1] = hreg[2] = hreg[3] = v; }

  __shared__ f32x4 part[3][3][64];           // waves 1..3 partials

  for (int t = 0; t < 512; ++t){
    // xp_t prefetch (wave0; issued before poll so latency hides under the spin)
    u16 xq[12];
    if (wv == 0){
      #pragma unroll
      for (int gt = 0; gt < 3; ++gt)
        #pragma unroll
        for (int r = 0; r < 4; ++r){
          int b = g * 16 + l4 * 4 + r;
          xq[gt * 4 + r] = xpb[((size_t)b * 512 + t) * 3072 + gt * 1024 + jb + l15];
        }
    }
    if (t > 0){
      // poll only the 16 slices this wave consumes (lanes duplicate across l4 -> 1-line txn)
      const int* fp_ = flags + ((size_t)g * 512 + (t - 1)) * 64 + wv * 16 + l15;
      while (true){
        int v = ld_coh_u32(fp_);
        wait_vm0();
        if (__all(v != 0)) break;
        __builtin_amdgcn_s_sleep(1);
      }
      __builtin_amdgcn_sched_barrier(0);
    }
    // A-fragment loads, fully coalesced from slice-major slab
    int rbuf = (t & 1) ^ 1;
    const char* hs = (const char*)hslab + (((size_t)rbuf * 4 + g) * 64 + wv * 16) * 512;
    const char* hl = hs + l15 * 32 + (l4 & 1) * 16;
    short8 af[8];
    #pragma unroll
    for (int ks = 0; ks < 8; ++ks)
      af[ks] = ld_cohx4((const u16*)(hl + (ks * 2 + (l4 >> 1)) * 512));
    wait_vm0();
    __builtin_amdgcn_sched_barrier(0);
    f32x4 a0 = {}, a1 = {}, a2 = {};
    #pragma unroll
    for (int ks = 0; ks < 8; ++ks){
      a0 = __builtin_amdgcn_mfma_f32_16x16x32_bf16(af[ks], wreg[0][ks], a0, 0, 0, 0);
      a1 = __builtin_amdgcn_mfma_f32_16x16x32_bf16(af[ks], wreg[1][ks], a1, 0, 0, 0);
      a2 = __builtin_amdgcn_mfma_f32_16x16x32_bf16(af[ks], wreg[2][ks], a2, 0, 0, 0);
    }
    if (wv){
      part[wv - 1][0][lane] = a0;
      part[wv - 1][1][lane] = a1;
      part[wv - 1][2][lane] = a2;
    }
    __syncthreads();
    // waves 1-3 race to t+1; their next part[] writes are gated by flag[t][own s], set only
    // after our wave0 reads part[] below -> no WAR hazard, barriers stay matched.
    if (wv == 0){
      f32x4 g0 = a0 + part[0][0][lane] + part[1][0][lane] + part[2][0][lane];
      f32x4 g1 = a1 + part[0][1][lane] + part[1][1][lane] + part[2][1][lane];
      f32x4 g2 = a2 + part[0][2][lane] + part[1][2][lane] + part[2][2][lane];
      int wb = t & 1;
      float hn_[4];
      #pragma unroll
      for (int r = 0; r < 4; ++r){
        float rr = sigm(bf2f(xq[r])      + g0[r] + bb0);
        float zz = sigm(bf2f(xq[4 + r])  + g1[r] + bb1);
        float nn = tanh_(bf2f(xq[8 + r]) + rr * (g2[r] + bb2));
        hn_[r] = (1.f - zz) * nn + zz * hreg[r];
        hreg[r] = hn_[r];
      }
      // store own 16x16 h-slice, slice-major (contiguous 512B block)
      u16* hw = hslab + (((size_t)wb * 4 + g) * 64 + s) * 256;
      #pragma unroll
      for (int r = 0; r < 4; ++r)
        st_coh_u16(hw + (l4 * 4 + r) * 16 + l15, f2bf(hn_[r]));
      wait_vm0();                                        // h at coherence point before flag
      if (lane == 0)
        st_coh_u32(flags + ((size_t)g * 512 + t) * 64 + s, 1);
      #pragma unroll
      for (int r = 0; r < 4; ++r)
        states[((size_t)(g * 16 + l4 * 4 + r) * 512 + t) * 1024 + jb + l15] = hn_[r];
    }
  }
}

// ---------------- outputs = states @ W_ly^T, pure fp32 (r9/r10-validated) ----------------
__global__ __launch_bounds__(256) void k_out(const float* __restrict__ st, const float* __restrict__ Wly,
                                             float* __restrict__ out)
{
  __shared__ float srow[8][1024];
  size_t m0 = (size_t)blockIdx.x * 8;
  int tid = threadIdx.x;
  for (int i = tid; i < 8 * 1024; i += 256)
    srow[i >> 10][i & 1023] = st[(m0 + (i >> 10)) * 1024 + (i & 1023)];
  __syncthreads();
  int mi = tid >> 5, o = tid & 31;
  const float* wp = Wly + (size_t)o * 1024;
  float acc = 0.f;
  #pragma unroll 4
  for (int k = 0; k < 1024; k += 4){
    f32x4 w = *(const f32x4*)(wp + k);
    f32x4 x = *(const f32x4*)(&srow[mi][k]);
    acc += x[0]*w[0] + x[1]*w[1] + x[2]*w[2] + x[3]*w[3];
  }
  out[(m0 + mi) * 32 + o] = acc;
}

extern "C" void kernel_launch(void* const* d_in, const int* in_sizes, int n_in,
                              void* d_out, int out_size, void* d_ws, size_t ws_size,
                              hipStream_t stream)
{
  const float* inputs = (const float*)d_in[0];
  const float* s0     = (const float*)d_in[1];
  const float* We     = (const float*)d_in[2];
  const float* be     = (const float*)d_in[3];
  const float* Wih    = (const float*)d_in[4];
  const float* bih    = (const float*)d_in[5];
  const float* Whh    = (const float*)d_in[6];
  const float* bhh    = (const float*)d_in[7];
  const float* Wly    = (const float*)d_in[8];

  float* out    = (float*)d_out;                 // (B,T,32)
  float* states = out + (size_t)64 * 512 * 32;   // (B,T,1024)

  char* ws = (char*)d_ws;
  u16* xe    = (u16*)ws;  ws += (size_t)32768 * 1024 * 2;
  u16* xpb   = (u16*)ws;  ws += (size_t)32768 * 3072 * 2;
  u16* Wihb  = (u16*)ws;  ws += (size_t)3072 * 1024 * 2;
  u16* Whhb  = (u16*)ws;  ws += (size_t)3072 * 1024 * 2;
  u16* hslab = (u16*)ws;  ws += (size_t)2 * 4 * 64 * 256 * 2;  // [buf][g][slice][16][16] bf16
  int* flags = (int*)ws;  ws += (size_t)4 * 512 * 64 * 4;      // [g][t][slice]

  k_init<<<dim3(4096), dim3(256), 0, stream>>>(Wih, Whh, s0, Wihb, Whhb, hslab, flags);
  k_xe<<<dim3(512), dim3(256), 0, stream>>>(inputs, We, be, xe);
  k_xp<<<dim3(6144), dim3(256), 0, stream>>>(xe, Wihb, bih, xpb);

  void* args[] = { (void*)&Whhb, (void*)&bhh, (void*)&xpb, (void*)&s0,
                   (void*)&hslab, (void*)&states, (void*)&flags };
  hipError_t e = hipLaunchCooperativeKernel((const void*)k_rec, dim3(256), dim3(256), args, 0, stream);
  if (e != hipSuccess){
    (void)hipGetLastError();
    k_rec<<<dim3(256), dim3(256), 0, stream>>>(Whhb, bhh, xpb, s0, hslab, states, flags);
  }
  k_out<<<dim3(4096), dim3(256), 0, stream>>>(states, Wly, out);
}

// Round 12
// 3367.155 us; speedup vs baseline: 1.5205x; 1.0674x over previous
//
#include <hip/hip_runtime.h>
#include <hip/hip_bf16.h>
#include <stdint.h>

typedef short short8 __attribute__((ext_vector_type(8)));
typedef float f32x4 __attribute__((ext_vector_type(4)));
typedef unsigned short u16;

__device__ __forceinline__ float bf2f(u16 b){ unsigned u = ((unsigned)b) << 16; float f; __builtin_memcpy(&f, &u, 4); return f; }
__device__ __forceinline__ u16 f2bf(float f){ unsigned u; __builtin_memcpy(&u, &f, 4); u = (u + 0x7fffu + ((u >> 16) & 1u)) >> 16; return (u16)u; }
__device__ __forceinline__ float sigm(float x){ return 1.f / (1.f + __expf(-x)); }
__device__ __forceinline__ float tanh_(float x){ float e = __expf(2.f * x); return 1.f - 2.f / (e + 1.f); }

// device-scope (coherence-point) accesses -- r3-proven protocol, verbatim
__device__ __forceinline__ short8 ld_cohx4(const u16* p){
  short8 d;
  asm volatile("global_load_dwordx4 %0, %1, off sc0 sc1" : "=v"(d) : "v"(p) : "memory");
  return d;
}
__device__ __forceinline__ int ld_coh_u32(const int* p){
  int d;
  asm volatile("global_load_dword %0, %1, off sc0 sc1" : "=v"(d) : "v"(p) : "memory");
  return d;
}
__device__ __forceinline__ void st_coh_u16(u16* p, u16 v){
  asm volatile("global_store_short %0, %1, off sc0 sc1" :: "v"(p), "v"(v) : "memory");
}
__device__ __forceinline__ void st_coh_u32(int* p, int v){
  asm volatile("global_store_dword %0, %1, off sc0 sc1" :: "v"(p), "v"(v) : "memory");
}
__device__ __forceinline__ void wait_vm0(){ asm volatile("s_waitcnt vmcnt(0)" ::: "memory"); }

// ---------------- init: bf16 weights, zero flags, h(-1)=state0 into slab buf 1 ----------------
// hslab layout: [buf(2)][g(4)][slice(64)][row(16)][col(16)] bf16  (512B per slice)
__global__ __launch_bounds__(256) void k_init(const float* __restrict__ Wih, const float* __restrict__ Whh,
                                              const float* __restrict__ s0,
                                              u16* __restrict__ Wihb, u16* __restrict__ Whhb,
                                              u16* __restrict__ hslab, int* __restrict__ flags)
{
  int i = blockIdx.x * 256 + threadIdx.x;
  int n = 3072 * 1024;
  for (int idx = i; idx < n; idx += gridDim.x * 256){
    Wihb[idx] = f2bf(Wih[idx]);
    Whhb[idx] = f2bf(Whh[idx]);
  }
  if (i < 65536){
    int k = ((i >> 8) & 63) * 16 + (i & 15);   // slice*16 + col
    hslab[65536 + i] = f2bf(s0[k]);
  }
  if (i < 4 * 512 * 64) flags[i] = 0;          // per-launch re-zero (graph replay safe)
}

// ---------------- xe = tanh(inputs @ W_e^T + b_e), stored bf16 [32768][1024] ----------------
__global__ __launch_bounds__(256) void k_xe(const float* __restrict__ inp, const float* __restrict__ We,
                                            const float* __restrict__ be, u16* __restrict__ xe)
{
  __shared__ float si[64][32];
  size_t m0 = (size_t)blockIdx.x * 64;
  int tid = threadIdx.x;
  for (int i = tid; i < 2048; i += 256)
    si[i >> 5][i & 31] = inp[m0 * 32 + i];
  __syncthreads();
  #pragma unroll
  for (int jj = 0; jj < 4; ++jj){
    int j = jj * 256 + tid;
    f32x4 wr[8];
    #pragma unroll
    for (int q = 0; q < 8; ++q)
      wr[q] = *(const f32x4*)(We + (size_t)j * 32 + q * 4);
    float bias = be[j];
    for (int mi = 0; mi < 64; ++mi){
      float acc = bias;
      #pragma unroll
      for (int q = 0; q < 8; ++q){
        f32x4 x = *(const f32x4*)(&si[mi][q * 4]);
        acc += x[0]*wr[q][0] + x[1]*wr[q][1] + x[2]*wr[q][2] + x[3]*wr[q][3];
      }
      xe[(m0 + mi) * 1024 + j] = f2bf(tanh_(acc));
    }
  }
}

// ---------------- GRU recurrence with FUSED xp: r3 protocol verbatim + xp(t+1) in the poll slack ----
// WG (g,s): 16 h-cols x 3 gates. Per step: poll (r3) -> h load -> h-MFMA -> part -> barrier ->
// wave0 reduce(part + xpart) + gate + h store + flag (r3 epilogue + fp32 xp sums) ->
// [slack filler] xe(t+1) + streamed W_ih frags (L2) -> 24 xp-MFMA -> xpart[(t+1)&1].
// xpart WAR: parity buffer + the existing barrier (wave0 reads xpart[t&1] post-barrier(t);
// waves rewrite that parity only after barrier(t+1), which waits for wave0). No new sync.
__global__ __launch_bounds__(256, 1) void k_rec(const u16* __restrict__ Whhb, const u16* __restrict__ Wihb,
                                                const float* __restrict__ bhh, const float* __restrict__ bih,
                                                const u16* __restrict__ xe, const float* __restrict__ s0,
                                                u16* __restrict__ hslab, float* __restrict__ states,
                                                int* __restrict__ flags)
{
  int w = blockIdx.x;
  int g = w & 3;                 // group
  int s = w >> 2;                // slice 0..63
  int jb = s * 16;
  int tid = threadIdx.x, lane = tid & 63, wv = tid >> 6;
  int l15 = lane & 15, l4 = lane >> 4;

  // persistent W_hh fragments (critical path): lane l15 = col-in-slice, wave wv owns K [wv*256,+256)
  short8 wreg[3][8];
  #pragma unroll
  for (int gt = 0; gt < 3; ++gt){
    const u16* wp = Whhb + (size_t)(gt * 1024 + jb + l15) * 1024 + wv * 256 + l4 * 8;
    #pragma unroll
    for (int ks = 0; ks < 8; ++ks)
      wreg[gt][ks] = *(const short8*)(wp + ks * 32);
  }
  float bb0 = bhh[jb + l15], bb1 = bhh[1024 + jb + l15], bb2 = bhh[2048 + jb + l15];
  float bi0 = bih[jb + l15], bi1 = bih[1024 + jb + l15], bi2 = bih[2048 + jb + l15];
  float hreg[4];
  { float v = s0[jb + l15]; hreg[0] = hreg[1] = hreg[2] = hreg[3] = v; }

  // W_ih slice pointers (streamed from L2 each step -- slack-filler, not critical path)
  const u16* wih0 = Wihb + (size_t)(jb + l15) * 1024 + wv * 256 + l4 * 8;
  const u16* wih1 = wih0 + (size_t)1024 * 1024;
  const u16* wih2 = wih1 + (size_t)1024 * 1024;
  // xe base for this lane's A-frag row (batch g*16+l15), k-slice of wave wv
  const u16* xeb = xe + ((size_t)(g * 16 + l15) * 512) * 1024 + wv * 256 + l4 * 8;

  __shared__ f32x4 part[3][3][64];          // h-side partials, waves 1..3
  __shared__ f32x4 xpart[2][3][3][64];      // xp partials, parity-double-buffered
  f32x4 cx0, cx1, cx2;                      // wave0's own xp partial (carried in regs)

  // ---- prologue: xp(0) ----
  {
    const u16* xp_ = xeb;                   // t = 0
    short8 ax[8];
    #pragma unroll
    for (int ks = 0; ks < 8; ++ks) ax[ks] = *(const short8*)(xp_ + ks * 32);
    f32x4 x0 = {}, x1 = {}, x2 = {};
    #pragma unroll
    for (int ks = 0; ks < 8; ++ks){
      short8 w0 = *(const short8*)(wih0 + ks * 32);
      short8 w1 = *(const short8*)(wih1 + ks * 32);
      short8 w2 = *(const short8*)(wih2 + ks * 32);
      x0 = __builtin_amdgcn_mfma_f32_16x16x32_bf16(ax[ks], w0, x0, 0, 0, 0);
      x1 = __builtin_amdgcn_mfma_f32_16x16x32_bf16(ax[ks], w1, x1, 0, 0, 0);
      x2 = __builtin_amdgcn_mfma_f32_16x16x32_bf16(ax[ks], w2, x2, 0, 0, 0);
    }
    if (wv){ xpart[0][wv - 1][0][lane] = x0; xpart[0][wv - 1][1][lane] = x1; xpart[0][wv - 1][2][lane] = x2; }
    else   { cx0 = x0; cx1 = x1; cx2 = x2; }
  }
  __syncthreads();

  for (int t = 0; t < 512; ++t){
    if (t > 0){
      // poll only the 16 slices this wave consumes (r3-verbatim)
      const int* fp_ = flags + ((size_t)g * 512 + (t - 1)) * 64 + wv * 16 + l15;
      while (true){
        int v = ld_coh_u32(fp_);
        wait_vm0();
        if (__all(v != 0)) break;
        __builtin_amdgcn_s_sleep(1);
      }
      __builtin_amdgcn_sched_barrier(0);
    }
    // A-fragment loads, fully coalesced from slice-major slab (r3-verbatim)
    int rbuf = (t & 1) ^ 1;
    const char* hs = (const char*)hslab + (((size_t)rbuf * 4 + g) * 64 + wv * 16) * 512;
    const char* hl = hs + l15 * 32 + (l4 & 1) * 16;
    short8 af[8];
    #pragma unroll
    for (int ks = 0; ks < 8; ++ks)
      af[ks] = ld_cohx4((const u16*)(hl + (ks * 2 + (l4 >> 1)) * 512));
    wait_vm0();
    __builtin_amdgcn_sched_barrier(0);
    f32x4 a0 = {}, a1 = {}, a2 = {};
    #pragma unroll
    for (int ks = 0; ks < 8; ++ks){
      a0 = __builtin_amdgcn_mfma_f32_16x16x32_bf16(af[ks], wreg[0][ks], a0, 0, 0, 0);
      a1 = __builtin_amdgcn_mfma_f32_16x16x32_bf16(af[ks], wreg[1][ks], a1, 0, 0, 0);
      a2 = __builtin_amdgcn_mfma_f32_16x16x32_bf16(af[ks], wreg[2][ks], a2, 0, 0, 0);
    }
    if (wv){
      part[wv - 1][0][lane] = a0;
      part[wv - 1][1][lane] = a1;
      part[wv - 1][2][lane] = a2;
    }
    __syncthreads();
    // (r3-verbatim WAR argument for part[]; xpart[] ordered by parity + this barrier)
    if (wv == 0){
      f32x4 g0 = a0 + part[0][0][lane] + part[1][0][lane] + part[2][0][lane];
      f32x4 g1 = a1 + part[0][1][lane] + part[1][1][lane] + part[2][1][lane];
      f32x4 g2 = a2 + part[0][2][lane] + part[1][2][lane] + part[2][2][lane];
      int pb = t & 1;
      f32x4 x0s = cx0 + xpart[pb][0][0][lane] + xpart[pb][1][0][lane] + xpart[pb][2][0][lane];
      f32x4 x1s = cx1 + xpart[pb][0][1][lane] + xpart[pb][1][1][lane] + xpart[pb][2][1][lane];
      f32x4 x2s = cx2 + xpart[pb][0][2][lane] + xpart[pb][1][2][lane] + xpart[pb][2][2][lane];
      int wb = t & 1;
      float hn_[4];
      #pragma unroll
      for (int r = 0; r < 4; ++r){
        float rr = sigm(x0s[r] + bi0 + g0[r] + bb0);
        float zz = sigm(x1s[r] + bi1 + g1[r] + bb1);
        float nn = tanh_(x2s[r] + bi2 + rr * (g2[r] + bb2));
        hn_[r] = (1.f - zz) * nn + zz * hreg[r];
        hreg[r] = hn_[r];
      }
      // store own 16x16 h-slice, slice-major (contiguous 512B block)
      u16* hw = hslab + (((size_t)wb * 4 + g) * 64 + s) * 256;
      #pragma unroll
      for (int r = 0; r < 4; ++r)
        st_coh_u16(hw + (l4 * 4 + r) * 16 + l15, f2bf(hn_[r]));
      wait_vm0();                                        // h at coherence point before flag
      if (lane == 0)
        st_coh_u32(flags + ((size_t)g * 512 + t) * 64 + s, 1);
      #pragma unroll
      for (int r = 0; r < 4; ++r)
        states[((size_t)(g * 16 + l4 * 4 + r) * 512 + t) * 1024 + jb + l15] = hn_[r];
    }
    // ---- slack filler: xp(t+1) (independent of recurrence; overlaps flag propagation) ----
    if (t + 1 < 512){
      const u16* xp_ = xeb + (size_t)(t + 1) * 1024;
      short8 ax[8];
      #pragma unroll
      for (int ks = 0; ks < 8; ++ks) ax[ks] = *(const short8*)(xp_ + ks * 32);
      f32x4 x0 = {}, x1 = {}, x2 = {};
      #pragma unroll
      for (int ks = 0; ks < 8; ++ks){
        short8 w0 = *(const short8*)(wih0 + ks * 32);
        short8 w1 = *(const short8*)(wih1 + ks * 32);
        short8 w2 = *(const short8*)(wih2 + ks * 32);
        x0 = __builtin_amdgcn_mfma_f32_16x16x32_bf16(ax[ks], w0, x0, 0, 0, 0);
        x1 = __builtin_amdgcn_mfma_f32_16x16x32_bf16(ax[ks], w1, x1, 0, 0, 0);
        x2 = __builtin_amdgcn_mfma_f32_16x16x32_bf16(ax[ks], w2, x2, 0, 0, 0);
      }
      int pb = (t + 1) & 1;
      if (wv){ xpart[pb][wv - 1][0][lane] = x0; xpart[pb][wv - 1][1][lane] = x1; xpart[pb][wv - 1][2][lane] = x2; }
      else   { cx0 = x0; cx1 = x1; cx2 = x2; }
    }
  }
}

// ---------------- outputs = states @ W_ly^T, pure fp32 (r9-r11 validated) ----------------
__global__ __launch_bounds__(256) void k_out(const float* __restrict__ st, const float* __restrict__ Wly,
                                             float* __restrict__ out)
{
  __shared__ float srow[8][1024];
  size_t m0 = (size_t)blockIdx.x * 8;
  int tid = threadIdx.x;
  for (int i = tid; i < 8 * 1024; i += 256)
    srow[i >> 10][i & 1023] = st[(m0 + (i >> 10)) * 1024 + (i & 1023)];
  __syncthreads();
  int mi = tid >> 5, o = tid & 31;
  const float* wp = Wly + (size_t)o * 1024;
  float acc = 0.f;
  #pragma unroll 4
  for (int k = 0; k < 1024; k += 4){
    f32x4 w = *(const f32x4*)(wp + k);
    f32x4 x = *(const f32x4*)(&srow[mi][k]);
    acc += x[0]*w[0] + x[1]*w[1] + x[2]*w[2] + x[3]*w[3];
  }
  out[(m0 + mi) * 32 + o] = acc;
}

extern "C" void kernel_launch(void* const* d_in, const int* in_sizes, int n_in,
                              void* d_out, int out_size, void* d_ws, size_t ws_size,
                              hipStream_t stream)
{
  const float* inputs = (const float*)d_in[0];
  const float* s0     = (const float*)d_in[1];
  const float* We     = (const float*)d_in[2];
  const float* be     = (const float*)d_in[3];
  const float* Wih    = (const float*)d_in[4];
  const float* bih    = (const float*)d_in[5];
  const float* Whh    = (const float*)d_in[6];
  const float* bhh    = (const float*)d_in[7];
  const float* Wly    = (const float*)d_in[8];

  float* out    = (float*)d_out;                 // (B,T,32)
  float* states = out + (size_t)64 * 512 * 32;   // (B,T,1024)

  char* ws = (char*)d_ws;
  u16* xe    = (u16*)ws;  ws += (size_t)32768 * 1024 * 2;
  u16* Wihb  = (u16*)ws;  ws += (size_t)3072 * 1024 * 2;
  u16* Whhb  = (u16*)ws;  ws += (size_t)3072 * 1024 * 2;
  u16* hslab = (u16*)ws;  ws += (size_t)2 * 4 * 64 * 256 * 2;  // [buf][g][slice][16][16] bf16
  int* flags = (int*)ws;  ws += (size_t)4 * 512 * 64 * 4;      // [g][t][slice]

  k_init<<<dim3(4096), dim3(256), 0, stream>>>(Wih, Whh, s0, Wihb, Whhb, hslab, flags);
  k_xe<<<dim3(512), dim3(256), 0, stream>>>(inputs, We, be, xe);

  void* args[] = { (void*)&Whhb, (void*)&Wihb, (void*)&bhh, (void*)&bih, (void*)&xe, (void*)&s0,
                   (void*)&hslab, (void*)&states, (void*)&flags };
  hipError_t e = hipLaunchCooperativeKernel((const void*)k_rec, dim3(256), dim3(256), args, 0, stream);
  if (e != hipSuccess){
    (void)hipGetLastError();
    k_rec<<<dim3(256), dim3(256), 0, stream>>>(Whhb, Wihb, bhh, bih, xe, s0, hslab, states, flags);
  }
  k_out<<<dim3(4096), dim3(256), 0, stream>>>(states, Wly, out);
}